// Round 1
// baseline (449.272 us; speedup 1.0000x reference)
//
#include <hip/hip_runtime.h>

#define NB 32
#define NN 2048
#define ND 64

typedef _Float16 half8 __attribute__((ext_vector_type(8)));
typedef float f32x4 __attribute__((ext_vector_type(4)));

union H4 { uint2 u; _Float16 h[4]; };

__device__ __forceinline__ f32x4 mfma16(half8 a, half8 b, f32x4 c) {
    return __builtin_amdgcn_mfma_f32_16x16x32_f16(a, b, c, 0, 0, 0);
}

// ---- pre-pass: f32 -> fp16 elementwise (8 elem/thread, fully coalesced) ----
__global__ __launch_bounds__(256) void cvt_f32_f16_k(const float* __restrict__ src,
                                                     _Float16* __restrict__ dst) {
    int i = blockIdx.x * 256 + threadIdx.x;     // grid sized exactly: n/8 threads
    const f32x4* s = (const f32x4*)src;
    f32x4 a = s[2 * i], b = s[2 * i + 1];
    half8 h;
    h[0] = (_Float16)a[0]; h[1] = (_Float16)a[1]; h[2] = (_Float16)a[2]; h[3] = (_Float16)a[3];
    h[4] = (_Float16)b[0]; h[5] = (_Float16)b[1]; h[6] = (_Float16)b[2]; h[7] = (_Float16)b[3];
    ((half8*)dst)[i] = h;
}

// ---- pre-pass: V[b][k][d] f32 -> Vt[b][d][k] fp16 via LDS 64x64 tile ----
__global__ __launch_bounds__(256) void transpose_v_k(const float* __restrict__ v,
                                                     _Float16* __restrict__ vt) {
    __shared__ float tile[64][65];
    int b = blockIdx.x >> 5;
    int k0 = (blockIdx.x & 31) * 64;
    int t = threadIdx.x;
    {
        int dc = t & 15, kr = t >> 4;
        const f32x4* vp = (const f32x4*)(v + ((size_t)(b * NN + k0) * ND));
        #pragma unroll
        for (int i = 0; i < 4; ++i) {
            int kk = kr + i * 16;
            f32x4 x = vp[kk * 16 + dc];
            tile[kk][dc * 4 + 0] = x[0]; tile[kk][dc * 4 + 1] = x[1];
            tile[kk][dc * 4 + 2] = x[2]; tile[kk][dc * 4 + 3] = x[3];
        }
    }
    __syncthreads();
    {
        int d = t >> 2, ks = (t & 3) * 16;
        union { _Float16 hh[16]; uint4 u4[2]; } pk;
        #pragma unroll
        for (int j = 0; j < 16; ++j) pk.hh[j] = (_Float16)tile[ks + j][d];
        uint4* op = (uint4*)(vt + ((size_t)(b * ND + d) * NN + k0 + ks));
        op[0] = pk.u4[0]; op[1] = pk.u4[1];
    }
}

// ---- main: per block = one (batch, 32-row Q tile) ----
// LDS: S[32][2048] fp16 = 128 KiB exactly, XOR-swizzled (byte ^= (row&7)<<4)
__global__ __launch_bounds__(256, 1) void attn_main_k(
        const _Float16* __restrict__ qh, const _Float16* __restrict__ kh,
        const _Float16* __restrict__ vt, const int* __restrict__ mask,
        float* __restrict__ outp, float* __restrict__ attnp) {
    extern __shared__ char smem[];

    // XCD-aware swizzle: consecutive resident blocks on an XCD share one batch's K/V in L2
    int bid = blockIdx.x;
    int lin = (bid & 7) * 256 + (bid >> 3);    // 2048 % 8 == 0 -> bijective
    int b  = lin >> 6;
    int q0 = (lin & 63) * 32;

    int t = threadIdx.x;
    int w = t >> 6, l = t & 63;
    int l15 = l & 15, lg = l >> 4;

    // Q fragments: A-frag layout row = lane&15, k = (lane>>4)*8 + j
    half8 afr[2][2];
    #pragma unroll
    for (int rb = 0; rb < 2; ++rb)
        #pragma unroll
        for (int ks = 0; ks < 2; ++ks)
            afr[rb][ks] = *(const half8*)(qh +
                ((size_t)(b * NN + q0 + rb * 16 + l15) * ND + ks * 32 + lg * 8));

    // ---- Phase 1: S = Q K^T / 8 -> LDS fp16 ----
    const _Float16* kbase = kh + (size_t)b * NN * ND;
    for (int i = 0; i < 32; ++i) {
        int key0 = (w + 4 * i) * 16;           // waves stride key tiles
        const _Float16* kp = kbase + (size_t)(key0 + l15) * ND + lg * 8;
        half8 b0 = *(const half8*)kp;
        half8 b1 = *(const half8*)(kp + 32);
        f32x4 acc0 = {0.f, 0.f, 0.f, 0.f};
        f32x4 acc1 = {0.f, 0.f, 0.f, 0.f};
        acc0 = mfma16(afr[0][0], b0, acc0);
        acc0 = mfma16(afr[0][1], b1, acc0);
        acc1 = mfma16(afr[1][0], b0, acc1);
        acc1 = mfma16(afr[1][1], b1, acc1);
        // C/D layout: col = lane&15, row = (lane>>4)*4 + reg  [m89-verified]
        int cb = (key0 + l15) * 2;
        #pragma unroll
        for (int r = 0; r < 4; ++r) {
            int row0 = lg * 4 + r;
            *(_Float16*)(smem + row0 * 4096 + (cb ^ ((row0 & 7) << 4))) =
                (_Float16)(acc0[r] * 0.125f);
            int row1 = row0 + 16;
            *(_Float16*)(smem + row1 * 4096 + (cb ^ ((row1 & 7) << 4))) =
                (_Float16)(acc1[r] * 0.125f);
        }
    }
    __syncthreads();

    // ---- Phase 2: mask + softmax stats (8 threads per row) ----
    int r = t >> 3, g = t & 7;
    char* srow = smem + r * 4096;
    int sw = (r & 7) << 4;
    const int4* mrow = (const int4*)(mask + ((size_t)(b * NN + q0 + r) * NN));
    float mx = -6.0e4f;
    for (int c = 0; c < 8; ++c) {
        int4 mk[8];                             // 8 int4 mask loads in flight
        #pragma unroll
        for (int u = 0; u < 8; ++u) mk[u] = mrow[(c * 8 + u) * 8 + g];
        #pragma unroll
        for (int u = 0; u < 8; ++u) {
            int kb = ((((c * 8 + u) * 8 + g) * 4) * 2) ^ sw;
            H4 x; x.u = *(const uint2*)(srow + kb);
            // masked -> -6e4: exp underflows to exactly 0 (matches -1e9 ref);
            // all-masked row -> m=-6e4, p=1 everywhere -> attn=1/N (matches ref)
            float s0 = mk[u].x > 0 ? (float)x.h[0] : -6.0e4f;
            float s1 = mk[u].y > 0 ? (float)x.h[1] : -6.0e4f;
            float s2 = mk[u].z > 0 ? (float)x.h[2] : -6.0e4f;
            float s3 = mk[u].w > 0 ? (float)x.h[3] : -6.0e4f;
            H4 y;
            y.h[0] = (_Float16)s0; y.h[1] = (_Float16)s1;
            y.h[2] = (_Float16)s2; y.h[3] = (_Float16)s3;
            *(uint2*)(srow + kb) = y.u;
            mx = fmaxf(mx, fmaxf(fmaxf(s0, s1), fmaxf(s2, s3)));
        }
    }
    #pragma unroll
    for (int s = 1; s < 8; s <<= 1) mx = fmaxf(mx, __shfl_xor(mx, s));

    float sum = 0.f;
    for (int c = 0; c < 8; ++c) {
        #pragma unroll
        for (int u = 0; u < 8; ++u) {
            int kb = ((((c * 8 + u) * 8 + g) * 4) * 2) ^ sw;
            H4 x; x.u = *(const uint2*)(srow + kb);
            float p0 = __expf((float)x.h[0] - mx);
            float p1 = __expf((float)x.h[1] - mx);
            float p2 = __expf((float)x.h[2] - mx);
            float p3 = __expf((float)x.h[3] - mx);
            sum += (p0 + p1) + (p2 + p3);
            H4 y;
            y.h[0] = (_Float16)p0; y.h[1] = (_Float16)p1;
            y.h[2] = (_Float16)p2; y.h[3] = (_Float16)p3;
            *(uint2*)(srow + kb) = y.u;
        }
    }
    #pragma unroll
    for (int s = 1; s < 8; s <<= 1) sum += __shfl_xor(sum, s);
    float linv = 1.0f / sum;

    // ---- Phase 3: write attn f32 + store normalized p back to LDS ----
    float* arow = attnp + ((size_t)(b * NN + q0 + r) * NN);
    for (int c = 0; c < 8; ++c) {
        #pragma unroll
        for (int u = 0; u < 8; ++u) {
            int k4 = ((c * 8 + u) * 8 + g) * 4;
            int kb = (k4 * 2) ^ sw;
            H4 x; x.u = *(const uint2*)(srow + kb);
            f32x4 av;
            av[0] = (float)x.h[0] * linv;
            av[1] = (float)x.h[1] * linv;
            av[2] = (float)x.h[2] * linv;
            av[3] = (float)x.h[3] * linv;
            *(f32x4*)(arow + k4) = av;
            H4 y;
            y.h[0] = (_Float16)av[0]; y.h[1] = (_Float16)av[1];
            y.h[2] = (_Float16)av[2]; y.h[3] = (_Float16)av[3];
            *(uint2*)(srow + kb) = y.u;
        }
    }
    __syncthreads();

    // ---- Phase 4: O = P V (P fp16 normalized in LDS, Vt fp16 from L2) ----
    int rb = w & 1, ct0 = (w >> 1) * 2;        // wave -> (row-block, 2 col-tiles)
    const _Float16* v0 = vt + (size_t)(b * ND + ct0 * 16 + l15) * NN;
    const _Float16* v1 = v0 + (size_t)16 * NN;
    int arowi = rb * 16 + l15;
    char* abase = smem + arowi * 4096;
    int asw = (arowi & 7) << 4;
    f32x4 o0 = {0.f, 0.f, 0.f, 0.f}, o1 = {0.f, 0.f, 0.f, 0.f};
    for (int ks = 0; ks < 64; ++ks) {
        int kb = (ks * 64 + lg * 16) ^ asw;
        half8 pa  = *(const half8*)(abase + kb);
        half8 vb0 = *(const half8*)(v0 + ks * 32 + lg * 8);
        half8 vb1 = *(const half8*)(v1 + ks * 32 + lg * 8);
        o0 = mfma16(pa, vb0, o0);
        o1 = mfma16(pa, vb1, o1);
    }
    float* ob = outp + ((size_t)(b * NN + q0 + rb * 16 + lg * 4) * ND) + ct0 * 16 + l15;
    #pragma unroll
    for (int rr = 0; rr < 4; ++rr) {
        ob[(size_t)rr * ND]      = o0[rr];
        ob[(size_t)rr * ND + 16] = o1[rr];
    }
}

extern "C" void kernel_launch(void* const* d_in, const int* in_sizes, int n_in,
                              void* d_out, int out_size, void* d_ws, size_t ws_size,
                              hipStream_t stream) {
    const float* q = (const float*)d_in[0];
    const float* k = (const float*)d_in[1];
    const float* v = (const float*)d_in[2];
    const int* mask = (const int*)d_in[3];
    float* outp  = (float*)d_out;
    float* attnp = outp + (size_t)NB * NN * ND;

    // workspace: qh (8MB) | kh (8MB) | vt (8MB)
    _Float16* qh = (_Float16*)d_ws;
    _Float16* kh = qh + (size_t)NB * NN * ND;
    _Float16* vth = kh + (size_t)NB * NN * ND;

    cvt_f32_f16_k<<<2048, 256, 0, stream>>>(q, qh);
    cvt_f32_f16_k<<<2048, 256, 0, stream>>>(k, kh);
    transpose_v_k<<<1024, 256, 0, stream>>>(v, vth);
    attn_main_k<<<2048, 256, 131072, stream>>>(qh, kh, vth, mask, outp, attnp);
}

// Round 2
// 409.600 us; speedup vs baseline: 1.0969x; 1.0969x over previous
//
#include <hip/hip_runtime.h>

#define NB 32
#define NN 2048
#define ND 64
#define ROWS 16
#define NBLK (NB * NN / ROWS)   // 4096 blocks

typedef _Float16 half8 __attribute__((ext_vector_type(8)));
typedef float f32x4 __attribute__((ext_vector_type(4)));

union H4 { uint2 u; _Float16 h[4]; };

__device__ __forceinline__ f32x4 mfma16(half8 a, half8 b, f32x4 c) {
    return __builtin_amdgcn_mfma_f32_16x16x32_f16(a, b, c, 0, 0, 0);
}

// ---- pre-pass: f32 -> fp16 elementwise (8 elem/thread, fully coalesced) ----
__global__ __launch_bounds__(256) void cvt_f32_f16_k(const float* __restrict__ src,
                                                     _Float16* __restrict__ dst) {
    int i = blockIdx.x * 256 + threadIdx.x;
    const f32x4* s = (const f32x4*)src;
    f32x4 a = s[2 * i], b = s[2 * i + 1];
    half8 h;
    h[0] = (_Float16)a[0]; h[1] = (_Float16)a[1]; h[2] = (_Float16)a[2]; h[3] = (_Float16)a[3];
    h[4] = (_Float16)b[0]; h[5] = (_Float16)b[1]; h[6] = (_Float16)b[2]; h[7] = (_Float16)b[3];
    ((half8*)dst)[i] = h;
}

// ---- pre-pass: V[b][k][d] f32 -> Vt[b][d][k] fp16 via LDS 64x64 tile ----
__global__ __launch_bounds__(256) void transpose_v_k(const float* __restrict__ v,
                                                     _Float16* __restrict__ vt) {
    __shared__ float tile[64][65];
    int b = blockIdx.x >> 5;
    int k0 = (blockIdx.x & 31) * 64;
    int t = threadIdx.x;
    {
        int dc = t & 15, kr = t >> 4;
        const f32x4* vp = (const f32x4*)(v + ((size_t)(b * NN + k0) * ND));
        #pragma unroll
        for (int i = 0; i < 4; ++i) {
            int kk = kr + i * 16;
            f32x4 x = vp[kk * 16 + dc];
            tile[kk][dc * 4 + 0] = x[0]; tile[kk][dc * 4 + 1] = x[1];
            tile[kk][dc * 4 + 2] = x[2]; tile[kk][dc * 4 + 3] = x[3];
        }
    }
    __syncthreads();
    {
        int d = t >> 2, ks = (t & 3) * 16;
        union { _Float16 hh[16]; uint4 u4[2]; } pk;
        #pragma unroll
        for (int j = 0; j < 16; ++j) pk.hh[j] = (_Float16)tile[ks + j][d];
        uint4* op = (uint4*)(vt + ((size_t)(b * ND + d) * NN + k0 + ks));
        op[0] = pk.u4[0]; op[1] = pk.u4[1];
    }
}

// ---- main: per block = one (batch, 16-row Q tile), 512 threads (8 waves) ----
// LDS: S[16][2048] fp16 = 64 KiB, XOR-swizzled (byte ^= (row&7)<<4)
// -> 2 blocks/CU, 16 waves/CU (~50% occupancy)
__global__ __launch_bounds__(512, 4) void attn_main_k(
        const _Float16* __restrict__ qh, const _Float16* __restrict__ kh,
        const _Float16* __restrict__ vt, const int* __restrict__ mask,
        float* __restrict__ outp, float* __restrict__ attnp) {
    extern __shared__ char smem[];

    // XCD-aware swizzle: consecutive lin on one XCD share a batch's K/V in its L2
    int bid = blockIdx.x;
    int lin = (bid & 7) * (NBLK / 8) + (bid >> 3);   // 4096 % 8 == 0 -> bijective
    int b  = lin >> 7;                                // 128 blocks per batch
    int q0 = (lin & 127) * ROWS;

    int t = threadIdx.x;
    int w = t >> 6, l = t & 63;
    int l15 = l & 15, lg = l >> 4;

    // Q fragments (A): row = lane&15, k = (lane>>4)*8 + j
    half8 afr[2];
    #pragma unroll
    for (int ks = 0; ks < 2; ++ks)
        afr[ks] = *(const half8*)(qh +
            ((size_t)(b * NN + q0 + l15) * ND + ks * 32 + lg * 8));

    // ---- Phase 1: S = Q K^T / 8 -> LDS fp16 (8 waves stride 128 key tiles) ----
    const _Float16* kbase = kh + (size_t)b * NN * ND;
    for (int i = 0; i < 16; ++i) {
        int key0 = (w + 8 * i) * 16;
        const _Float16* kp = kbase + (size_t)(key0 + l15) * ND + lg * 8;
        half8 b0 = *(const half8*)kp;
        half8 b1 = *(const half8*)(kp + 32);
        f32x4 acc = {0.f, 0.f, 0.f, 0.f};
        acc = mfma16(afr[0], b0, acc);
        acc = mfma16(afr[1], b1, acc);
        // C/D layout: col = lane&15, row = (lane>>4)*4 + reg
        int cb = (key0 + l15) * 2;
        #pragma unroll
        for (int r = 0; r < 4; ++r) {
            int row = lg * 4 + r;
            *(_Float16*)(smem + row * 4096 + (cb ^ ((row & 7) << 4))) =
                (_Float16)(acc[r] * 0.125f);
        }
    }
    __syncthreads();

    // ---- Phase 2: mask + softmax, scores cached in registers ----
    // 32 threads per row; thread g owns cols {g*4 + j*128}, j=0..15 (coalesced)
    int r = t >> 5, g = t & 31;
    char* srow = smem + r * 4096;
    int sw = (r & 7) << 4;
    const int4* mrow = (const int4*)(mask + ((size_t)(b * NN + q0 + r) * NN));
    uint2 ms[16];
    float mx = -6.0e4f;
    #pragma unroll
    for (int c = 0; c < 2; ++c) {
        int4 mk[8];                              // 8 int4 mask loads in flight
        #pragma unroll
        for (int u = 0; u < 8; ++u) mk[u] = mrow[g + (c * 8 + u) * 32];
        #pragma unroll
        for (int u = 0; u < 8; ++u) {
            int j = c * 8 + u;
            int kb = ((g * 4 + j * 128) * 2) ^ sw;
            H4 x; x.u = *(const uint2*)(srow + kb);
            // masked -> -6e4: exp underflows to exactly 0 (matches -1e9 ref);
            // all-masked row -> m=-6e4, p=1 everywhere -> attn=1/N (matches ref)
            float s0 = mk[u].x > 0 ? (float)x.h[0] : -6.0e4f;
            float s1 = mk[u].y > 0 ? (float)x.h[1] : -6.0e4f;
            float s2 = mk[u].z > 0 ? (float)x.h[2] : -6.0e4f;
            float s3 = mk[u].w > 0 ? (float)x.h[3] : -6.0e4f;
            H4 y;
            y.h[0] = (_Float16)s0; y.h[1] = (_Float16)s1;
            y.h[2] = (_Float16)s2; y.h[3] = (_Float16)s3;
            ms[j] = y.u;
            mx = fmaxf(mx, fmaxf(fmaxf(s0, s1), fmaxf(s2, s3)));
        }
    }
    #pragma unroll
    for (int s = 1; s < 32; s <<= 1) mx = fmaxf(mx, __shfl_xor(mx, s));

    float sum = 0.f;
    #pragma unroll
    for (int j = 0; j < 16; ++j) {
        H4 x; x.u = ms[j];
        float p0 = __expf((float)x.h[0] - mx);
        float p1 = __expf((float)x.h[1] - mx);
        float p2 = __expf((float)x.h[2] - mx);
        float p3 = __expf((float)x.h[3] - mx);
        sum += (p0 + p1) + (p2 + p3);
        H4 y;
        y.h[0] = (_Float16)p0; y.h[1] = (_Float16)p1;
        y.h[2] = (_Float16)p2; y.h[3] = (_Float16)p3;
        ms[j] = y.u;
    }
    #pragma unroll
    for (int s = 1; s < 32; s <<= 1) sum += __shfl_xor(sum, s);
    float linv = 1.0f / sum;

    // ---- Phase 3: write attn f32 (coalesced f32x4) + normalized p -> LDS ----
    float* arow = attnp + ((size_t)(b * NN + q0 + r) * NN);
    #pragma unroll
    for (int j = 0; j < 16; ++j) {
        int col = g * 4 + j * 128;
        H4 x; x.u = ms[j];
        f32x4 av;
        av[0] = (float)x.h[0] * linv;
        av[1] = (float)x.h[1] * linv;
        av[2] = (float)x.h[2] * linv;
        av[3] = (float)x.h[3] * linv;
        *(f32x4*)(arow + col) = av;
        H4 y;
        y.h[0] = (_Float16)av[0]; y.h[1] = (_Float16)av[1];
        y.h[2] = (_Float16)av[2]; y.h[3] = (_Float16)av[3];
        *(uint2*)(srow + (col * 2 ^ sw)) = y.u;
    }
    __syncthreads();

    // ---- Phase 4: O = P V. 8 waves = 4 col-tiles x 2 k-segments ----
    int ct = w & 3, kseg = w >> 2;
    const _Float16* vp = vt + (size_t)(b * ND + ct * 16 + l15) * NN + lg * 8;
    char* abase = smem + l15 * 4096;
    int asw = (l15 & 7) << 4;
    f32x4 o = {0.f, 0.f, 0.f, 0.f};
    #pragma unroll 4
    for (int kk = 0; kk < 32; ++kk) {
        int ks = kseg * 32 + kk;
        half8 pa = *(const half8*)(abase + ((ks * 64 + lg * 16) ^ asw));
        half8 vb = *(const half8*)(vp + ks * 32);
        o = mfma16(pa, vb, o);
    }
    // combine the two k-segments via LDS partials (smem reuse is post-sync)
    __syncthreads();
    if (w >= 4) *(f32x4*)(smem + ((w - 4) * 64 + l) * 16) = o;
    __syncthreads();
    if (w < 4) {
        f32x4 o2 = *(const f32x4*)(smem + (w * 64 + l) * 16);
        o += o2;
        float* ob = outp + ((size_t)(b * NN + q0 + lg * 4) * ND) + ct * 16 + l15;
        #pragma unroll
        for (int rr = 0; rr < 4; ++rr) ob[(size_t)rr * ND] = o[rr];
    }
}

extern "C" void kernel_launch(void* const* d_in, const int* in_sizes, int n_in,
                              void* d_out, int out_size, void* d_ws, size_t ws_size,
                              hipStream_t stream) {
    const float* q = (const float*)d_in[0];
    const float* k = (const float*)d_in[1];
    const float* v = (const float*)d_in[2];
    const int* mask = (const int*)d_in[3];
    float* outp  = (float*)d_out;
    float* attnp = outp + (size_t)NB * NN * ND;

    _Float16* qh = (_Float16*)d_ws;
    _Float16* kh = qh + (size_t)NB * NN * ND;
    _Float16* vth = kh + (size_t)NB * NN * ND;

    cvt_f32_f16_k<<<2048, 256, 0, stream>>>(q, qh);
    cvt_f32_f16_k<<<2048, 256, 0, stream>>>(k, kh);
    transpose_v_k<<<1024, 256, 0, stream>>>(v, vth);
    attn_main_k<<<NBLK, 512, 65536, stream>>>(qh, kh, vth, mask, outp, attnp);
}